// Round 14
// baseline (273.459 us; speedup 1.0000x reference)
//
#include <hip/hip_runtime.h>

#define INV_STD 0.9999950000374997f

typedef unsigned short u16;
typedef __bf16 bf16x8 __attribute__((ext_vector_type(8)));
typedef float f32x4 __attribute__((ext_vector_type(4)));

__device__ __forceinline__ u16 f2bf(float f) {
    unsigned int u = __float_as_uint(f);
    u += 0x7fffu + ((u >> 16) & 1u);   // RNE
    return (u16)(u >> 16);
}

// async global->LDS, 16B per lane. LDS dest must be wave-uniform base (HW adds lane*16).
__device__ __forceinline__ void gl_lds16(const void* g, void* l) {
    __builtin_amdgcn_global_load_lds(
        (const __attribute__((address_space(1))) unsigned int*)(unsigned long long)g,
        (__attribute__((address_space(3))) unsigned int*)(unsigned int)(unsigned long long)l,
        16, 0, 0);
}

__device__ __forceinline__ f32x4 mfma16(bf16x8 a, bf16x8 b, f32x4 c) {
    return __builtin_amdgcn_mfma_f32_16x16x32_bf16(a, b, c, 0, 0, 0);
}

__device__ __forceinline__ bf16x8 ldg8(const u16* p) {
    return *(const bf16x8*)p;
}

// ---------------- ONE prep kernel: kv(+WoV fold) in blocks 0..255, weight conversions after ----------------
__global__ __launch_bounds__(256) void prep_kernel(
    const float* __restrict__ proxy,                       // (B,512,19)
    const float* __restrict__ wk1, const float* __restrict__ gk1, const float* __restrict__ bk1,
    const float* __restrict__ wk2, const float* __restrict__ gk2, const float* __restrict__ bk2,
    const float* __restrict__ wv,  const float* __restrict__ gv,  const float* __restrict__ bv,
    const float* __restrict__ wo,  const float* __restrict__ go,
    const float* __restrict__ wq1, const float* __restrict__ gq1,
    const float* __restrict__ wq2, const float* __restrict__ gq2,
    u16* __restrict__ KB,                                  // (B,32,256) bf16, rows 19..31 zero
    u16* __restrict__ WoVB,                                // (B,512,32) bf16, cols 19..31 zero
    u16* __restrict__ WQ1B, u16* __restrict__ WQ2B)
{
    int blk = blockIdx.x;
    int t = threadIdx.x;
    if (blk >= 256) {
        if (blk < 768) {            // WQ1B (natural K order)
            long i = (long)(blk - 256) * 256 + t;
            int o = (int)(i >> 9);
            WQ1B[i] = f2bf(wq1[i] * (INV_STD * gq1[o]));
        } else {                    // WQ2B
            long i = (long)(blk - 768) * 256 + t;
            int o = (int)(i >> 8);
            WQ2B[i] = f2bf(wq2[i] * (INV_STD * gq2[o]));
        }
        return;
    }
    // ---- kv + WoV fold: block (b,p) ----
    int b = blk >> 5, p = blk & 31;
    if (p >= 19) {                  // zero padding
        KB[((long)b * 32 + p) * 256 + t] = 0;
        WoVB[((long)b * 512 + t) * 32 + p] = 0;
        WoVB[((long)b * 512 + 256 + t) * 32 + p] = 0;
        return;
    }
    __shared__ float px[512];
    __shared__ float k1[256];
    __shared__ float vcol[256];
    for (int i = t; i < 512; i += 256) px[i] = proxy[((long)b * 512 + i) * 19 + p];
    __syncthreads();
    float aK = 0.f, aV = 0.f;
    {
        const float4* wk1r = (const float4*)(wk1 + (long)t * 512);
        const float4* wvr  = (const float4*)(wv  + (long)t * 512);
        const float4* pxv  = (const float4*)px;
        #pragma unroll 4
        for (int c = 0; c < 128; ++c) {
            float4 pv = pxv[c];
            float4 k4 = wk1r[c];
            float4 v4 = wvr[c];
            aK += k4.x * pv.x + k4.y * pv.y + k4.z * pv.z + k4.w * pv.w;
            aV += v4.x * pv.x + v4.y * pv.y + v4.z * pv.z + v4.w * pv.w;
        }
    }
    float k1v = fmaxf(aK * (INV_STD * gk1[t]) + bk1[t], 0.f);
    float vv  = fmaxf(aV * (INV_STD * gv[t])  + bv[t],  0.f);
    k1[t] = k1v;
    vcol[t] = vv;
    __syncthreads();
    // k2 dot -> KB
    {
        float a2 = 0.f;
        const float4* wk2r = (const float4*)(wk2 + (long)t * 256);
        const float4* k1v4 = (const float4*)k1;
        #pragma unroll 4
        for (int c = 0; c < 64; ++c) {
            float4 w4 = wk2r[c];
            float4 kk = k1v4[c];
            a2 += w4.x * kk.x + w4.y * kk.y + w4.z * kk.z + w4.w * kk.w;
        }
        KB[((long)b * 32 + p) * 256 + t] = f2bf(fmaxf(a2 * (INV_STD * gk2[t]) + bk2[t], 0.f));
    }
    // WoV fold: thread t -> channels t and t+256, column p
    {
        float a0 = 0.f, a1 = 0.f;
        const float4* wr0 = (const float4*)(wo + (long)t * 256);
        const float4* wr1 = (const float4*)(wo + (long)(t + 256) * 256);
        const float4* vc4 = (const float4*)vcol;
        #pragma unroll 4
        for (int c = 0; c < 64; ++c) {
            float4 v4 = vc4[c];
            float4 w0 = wr0[c];
            float4 w1 = wr1[c];
            a0 += w0.x * v4.x + w0.y * v4.y + w0.z * v4.z + w0.w * v4.w;
            a1 += w1.x * v4.x + w1.y * v4.y + w1.z * v4.z + w1.w * v4.w;
        }
        WoVB[((long)b * 512 + t) * 32 + p] = f2bf(INV_STD * go[t] * a0);
        WoVB[((long)b * 512 + 256 + t) * 32 + p] = f2bf(INV_STD * go[t + 256] * a1);
    }
}

// ---------------- fully fused: gemm1 -> gemm2 -> attention -> (att · WoV^T) ----------------
// Per 64-pixel block, 4 waves, 2 blocks/CU.
// Phase A is BARRIER-FREE: x A-frags loaded per-lane direct from global (lane=pixel, k=channel),
// W1 B-frags K-contiguous ldg8. No LDS, no transpose, no sigma permute.
__global__ __launch_bounds__(256, 2) void fused_all(
    const float* __restrict__ X,     // (B,512,16384) f32
    const u16* __restrict__ W1,      // (256,512) bf16
    const float* __restrict__ b1,
    const u16* __restrict__ W2,      // (256,256) bf16
    const float* __restrict__ b2,
    const u16* __restrict__ KB,      // (B,32,256) bf16
    const u16* __restrict__ WoVB,    // (B,512,32) bf16
    const float* __restrict__ obias,
    float* __restrict__ out)         // (B,512,16384) f32
{
    __shared__ __align__(16) u16 lB[2][256 * 32];  // 32 KB, W2 staging (dbuf)
    __shared__ __align__(16) u16 q12s[64 * 264];   // 33 KB: q1 -> q2
    __shared__ __align__(16) u16 atts[64 * 40];    //  5 KB
    int t = threadIdx.x, lane = t & 63, w = t >> 6;
    int l16 = lane & 15, hi = lane >> 4;
    long m0 = (long)blockIdx.x * 64;
    int b = (int)(m0 >> 14);
    int pixg = (int)(m0 & 16383);
    const float* xb = X + (long)b * 512 * 16384 + pixg;
    int rW = lane >> 2;            // staging row within 16-row group
    int cW = (lane & 3) << 3;      // staging col (u16)

    // ================= phase A: gemm1, q1 = relu(x^T · W1^T + b1); barrier-free =================
    {
        f32x4 acc[4][4] = {};
        #pragma unroll
        for (int kt = 0; kt < 8; ++kt) {
            int k0 = kt << 6;
            #pragma unroll
            for (int kk = 0; kk < 2; ++kk) {
                int kc = k0 + kk * 32 + hi * 8;
                bf16x8 bb[4];
                #pragma unroll
                for (int j = 0; j < 4; ++j)
                    bb[j] = ldg8(W1 + (long)(w * 64 + j * 16 + l16) * 512 + kc);
                #pragma unroll
                for (int i = 0; i < 4; ++i) {
                    const float* xp = xb + (long)kc * 16384 + i * 16 + l16;
                    bf16x8 a;
                    #pragma unroll
                    for (int e = 0; e < 8; ++e)
                        a[e] = (__bf16)xp[(long)e * 16384];
                    #pragma unroll
                    for (int j = 0; j < 4; ++j)
                        acc[i][j] = mfma16(a, bb[j], acc[i][j]);
                }
            }
        }
        // epilogue: q1 -> q12s (bf16), and prefetch W2 chunk 0 into lB[0]
        #pragma unroll
        for (int j = 0; j < 4; ++j) {
            int q = w * 4 + j;
            gl_lds16(W2 + (long)(q * 16 + rW) * 256 + cW, &lB[0][q * 512]);
        }
        float bj[4];
        #pragma unroll
        for (int j = 0; j < 4; ++j) bj[j] = b1[w * 64 + j * 16 + l16];
        #pragma unroll
        for (int i = 0; i < 4; ++i)
            #pragma unroll
            for (int r = 0; r < 4; ++r) {
                int pix = i * 16 + hi * 4 + r;
                #pragma unroll
                for (int j = 0; j < 4; ++j) {
                    float v = acc[i][j][r] + bj[j];
                    q12s[pix * 264 + w * 64 + j * 16 + l16] = f2bf(fmaxf(v, 0.f));
                }
            }
    }
    __syncthreads();       // q1 visible + W2 chunk0 staged (full drain required for DMA)
    // ================= phase B: gemm2, q2 = relu(q1 · W2^T + b2) =================
    {
        f32x4 acc[4][4] = {};
        #pragma unroll
        for (int c = 0; c < 8; ++c) {
            int cur = c & 1;
            if (c < 7) {                         // stage next W2 chunk (issue-early)
                int k1 = (c + 1) << 5;
                #pragma unroll
                for (int j = 0; j < 4; ++j) {
                    int q = w * 4 + j;
                    gl_lds16(W2 + (long)(q * 16 + rW) * 256 + k1 + cW, &lB[cur ^ 1][q * 512]);
                }
            }
            bf16x8 a[4], bb[4];
            #pragma unroll
            for (int i = 0; i < 4; ++i)
                a[i] = *(const bf16x8*)&q12s[(i * 16 + l16) * 264 + (c << 5) + hi * 8];
            #pragma unroll
            for (int j = 0; j < 4; ++j)
                bb[j] = *(const bf16x8*)&lB[cur][(w * 64 + j * 16 + l16) * 32 + hi * 8];
            #pragma unroll
            for (int i = 0; i < 4; ++i)
                #pragma unroll
                for (int j = 0; j < 4; ++j)
                    acc[i][j] = mfma16(a[i], bb[j], acc[i][j]);
            __syncthreads();                     // drains next-chunk DMA (overlapped)
        }
        // epilogue: q2 -> q12s (all q1 reads complete after last sync)
        float bj[4];
        #pragma unroll
        for (int j = 0; j < 4; ++j) bj[j] = b2[w * 64 + j * 16 + l16];
        #pragma unroll
        for (int i = 0; i < 4; ++i)
            #pragma unroll
            for (int r = 0; r < 4; ++r) {
                int pix = i * 16 + hi * 4 + r;
                #pragma unroll
                for (int j = 0; j < 4; ++j) {
                    float v = acc[i][j][r] + bj[j];
                    q12s[pix * 264 + w * 64 + j * 16 + l16] = f2bf(fmaxf(v, 0.f));
                }
            }
    }
    __syncthreads();
    // ================= phase C: sim = q2 · KB^T, softmax -> atts =================
    {
        f32x4 s0 = {}, s1 = {};
        #pragma unroll
        for (int ks = 0; ks < 8; ++ks) {
            bf16x8 a = *(const bf16x8*)&q12s[(w * 16 + l16) * 264 + ks * 32 + hi * 8];
            bf16x8 b0 = ldg8(KB + ((long)b * 32 + l16) * 256 + ks * 32 + hi * 8);
            bf16x8 b1v = ldg8(KB + ((long)b * 32 + 16 + l16) * 256 + ks * 32 + hi * 8);
            s0 = mfma16(a, b0, s0);
            s1 = mfma16(a, b1v, s1);
        }
        const float scale = 0.0625f;
        #pragma unroll
        for (int r = 0; r < 4; ++r) {
            float v0 = s0[r] * scale;
            float v1 = s1[r] * scale;
            float mx = fmaxf(v0, v1);
            mx = fmaxf(mx, __shfl_xor(mx, 1));
            mx = fmaxf(mx, __shfl_xor(mx, 2));
            mx = fmaxf(mx, __shfl_xor(mx, 4));
            mx = fmaxf(mx, __shfl_xor(mx, 8));
            float e0 = __expf(v0 - mx);
            float e1 = (l16 < 3) ? __expf(v1 - mx) : 0.f;
            float s = e0 + e1;
            s += __shfl_xor(s, 1);
            s += __shfl_xor(s, 2);
            s += __shfl_xor(s, 4);
            s += __shfl_xor(s, 8);
            float inv = 1.f / s;
            int pix = w * 16 + hi * 4 + r;
            atts[pix * 40 + l16] = f2bf(e0 * inv);
            atts[pix * 40 + 16 + l16] = (l16 < 3) ? f2bf(e1 * inv) : (u16)0;
        }
    }
    __syncthreads();       // atts visible to all waves
    // ================= phase D': out = relu(att · WoV^T + bo); K=32, 0 barriers =================
    {
        bf16x8 av[4], bv[8];
        #pragma unroll
        for (int mf = 0; mf < 4; ++mf)
            av[mf] = *(const bf16x8*)&atts[(mf * 16 + l16) * 40 + hi * 8];
        #pragma unroll
        for (int nf = 0; nf < 8; ++nf)
            bv[nf] = ldg8(WoVB + ((long)b * 512 + w * 128 + nf * 16 + l16) * 32 + hi * 8);
        #pragma unroll
        for (int nf = 0; nf < 8; ++nf) {
            int ch = w * 128 + nf * 16 + l16;
            float bc = obias[ch];
            float* orow = out + ((long)b * 512 + ch) * 16384 + pixg;
            #pragma unroll
            for (int mf = 0; mf < 4; ++mf) {
                f32x4 acc = mfma16(av[mf], bv[nf], (f32x4){0.f, 0.f, 0.f, 0.f});
                float4 v;
                v.x = fmaxf(acc[0] + bc, 0.f);
                v.y = fmaxf(acc[1] + bc, 0.f);
                v.z = fmaxf(acc[2] + bc, 0.f);
                v.w = fmaxf(acc[3] + bc, 0.f);
                *(float4*)&orow[mf * 16 + hi * 4] = v;
            }
        }
    }
}

extern "C" void kernel_launch(void* const* d_in, const int* in_sizes, int n_in,
                              void* d_out, int out_size, void* d_ws, size_t ws_size,
                              hipStream_t stream) {
    const float* x    = (const float*)d_in[0];
    const float* prox = (const float*)d_in[1];
    const float* wq1  = (const float*)d_in[2];
    const float* gq1  = (const float*)d_in[3];
    const float* bq1  = (const float*)d_in[4];
    const float* wq2  = (const float*)d_in[5];
    const float* gq2  = (const float*)d_in[6];
    const float* bq2  = (const float*)d_in[7];
    const float* wk1  = (const float*)d_in[8];
    const float* gk1  = (const float*)d_in[9];
    const float* bk1  = (const float*)d_in[10];
    const float* wk2  = (const float*)d_in[11];
    const float* gk2  = (const float*)d_in[12];
    const float* bk2  = (const float*)d_in[13];
    const float* wv   = (const float*)d_in[14];
    const float* gv   = (const float*)d_in[15];
    const float* bv   = (const float*)d_in[16];
    const float* wo   = (const float*)d_in[17];
    const float* go   = (const float*)d_in[18];
    const float* bo   = (const float*)d_in[19];
    float* out = (float*)d_out;

    char* ws = (char*)d_ws;
    u16* KB   = (u16*)(ws);                      // 128 KB
    u16* WoVB = (u16*)(ws + 131072);             // 256 KB
    u16* WQ1B = (u16*)(ws + 393216);             // 256 KB
    u16* WQ2B = (u16*)(ws + 655360);             // 128 KB

    prep_kernel<<<1024, 256, 0, stream>>>(prox, wk1, gk1, bk1, wk2, gk2, bk2, wv, gv, bv,
                                          wo, go, wq1, gq1, wq2, gq2, KB, WoVB, WQ1B, WQ2B);
    fused_all<<<2048, 256, 0, stream>>>(x, WQ1B, bq1, WQ2B, bq2, KB, WoVB, bo, out);
}

// Round 15
// 202.186 us; speedup vs baseline: 1.3525x; 1.3525x over previous
//
#include <hip/hip_runtime.h>

#define INV_STD 0.9999950000374997f

typedef unsigned short u16;
typedef __bf16 bf16x8 __attribute__((ext_vector_type(8)));
typedef __bf16 bf16x4 __attribute__((ext_vector_type(4)));
typedef float f32x4 __attribute__((ext_vector_type(4)));

__device__ __forceinline__ u16 f2bf(float f) {
    unsigned int u = __float_as_uint(f);
    u += 0x7fffu + ((u >> 16) & 1u);   // RNE
    return (u16)(u >> 16);
}

// async global->LDS, 16B per lane. LDS dest must be wave-uniform base (HW adds lane*16).
__device__ __forceinline__ void gl_lds16(const void* g, void* l) {
    __builtin_amdgcn_global_load_lds(
        (const __attribute__((address_space(1))) unsigned int*)(unsigned long long)g,
        (__attribute__((address_space(3))) unsigned int*)(unsigned int)(unsigned long long)l,
        16, 0, 0);
}

__device__ __forceinline__ f32x4 mfma16(bf16x8 a, bf16x8 b, f32x4 c) {
    return __builtin_amdgcn_mfma_f32_16x16x32_bf16(a, b, c, 0, 0, 0);
}

__device__ __forceinline__ unsigned lds_off(const void* p) {
    return (unsigned)(unsigned long long)p;
}

// hardware transpose read: lane reads 4 bf16 at byte addr +0,+32,+64,+96
__device__ __forceinline__ bf16x4 tr_read(unsigned addr) {
    bf16x4 r;
    asm volatile("ds_read_b64_tr_b16 %0, %1" : "=v"(r) : "v"(addr));
    return r;
}

__device__ __forceinline__ bf16x8 ldg8(const u16* p) {
    return *(const bf16x8*)p;
}

// ---------------- prep0: weight bf16 conversions + f32 transposes ----------------
// blocks 0..511: WQ1B (K-permuted); 512..767: WQ2B;
// 768..799 wk1T; 800..831 wvT; 832..863 woT; 864..879 wk2T.
__device__ __forceinline__ void xpose_tile(const float* __restrict__ src, float* __restrict__ dst,
                                           int O, int C, int o0, int c0, int t) {
    __shared__ float tile[64][65];
    #pragma unroll
    for (int q = 0; q < 16; ++q) {
        int idx = q * 256 + t;
        int r = idx >> 6, cc = idx & 63;
        tile[r][cc] = src[(long)(o0 + r) * C + c0 + cc];
    }
    __syncthreads();
    #pragma unroll
    for (int q = 0; q < 16; ++q) {
        int idx = q * 256 + t;
        int r = idx >> 6, cc = idx & 63;
        dst[(long)(c0 + r) * O + o0 + cc] = tile[cc][r];
    }
}

__global__ __launch_bounds__(256) void prep0(
    const float* __restrict__ wq1, const float* __restrict__ gq1,
    const float* __restrict__ wq2, const float* __restrict__ gq2,
    const float* __restrict__ wk1, const float* __restrict__ wv,
    const float* __restrict__ wo,  const float* __restrict__ wk2,
    u16* __restrict__ WQ1B, u16* __restrict__ WQ2B,
    float* __restrict__ wk1T, float* __restrict__ wvT,
    float* __restrict__ woT,  float* __restrict__ wk2T)
{
    int blk = blockIdx.x;
    int t = threadIdx.x;
    if (blk < 512) {                 // WQ1B, K-permuted (sigma matches fused tr-read order)
        long i = (long)blk * 256 + t;
        int o = (int)(i >> 9);
        int q = (int)(i & 511);
        int r = q & 31;
        int src = (q & ~31) + ((r >> 3) & 3) * 4 + (r & 3) + ((r >> 2) & 1) * 16;
        WQ1B[i] = f2bf(wq1[(long)o * 512 + src] * (INV_STD * gq1[o]));
    } else if (blk < 768) {          // WQ2B
        long i = (long)(blk - 512) * 256 + t;
        int o = (int)(i >> 8);
        WQ2B[i] = f2bf(wq2[i] * (INV_STD * gq2[o]));
    } else if (blk < 800) {          // wk1 (256,512) -> wk1T (512,256)
        int id = blk - 768;
        xpose_tile(wk1, wk1T, 256, 512, (id & 3) * 64, (id >> 2) * 64, t);
    } else if (blk < 832) {          // wv (256,512) -> wvT (512,256)
        int id = blk - 800;
        xpose_tile(wv, wvT, 256, 512, (id & 3) * 64, (id >> 2) * 64, t);
    } else if (blk < 864) {          // wo (512,256) -> woT (256,512)
        int id = blk - 832;
        xpose_tile(wo, woT, 512, 256, (id >> 2) * 64, (id & 3) * 64, t);
    } else {                         // wk2 (256,256) -> wk2T (256,256)
        int id = blk - 864;
        xpose_tile(wk2, wk2T, 256, 256, (id >> 2) * 64, (id & 3) * 64, t);
    }
}

// ---------------- prep1: kv + WoV fold, coalesced via transposed weights ----------------
__global__ __launch_bounds__(256) void prep1(
    const float* __restrict__ proxy,                       // (B,512,19)
    const float* __restrict__ wk1T, const float* __restrict__ gk1, const float* __restrict__ bk1,
    const float* __restrict__ wk2T, const float* __restrict__ gk2, const float* __restrict__ bk2,
    const float* __restrict__ wvT,  const float* __restrict__ gv,  const float* __restrict__ bv,
    const float* __restrict__ woT,  const float* __restrict__ go,
    u16* __restrict__ KB,                                  // (B,32,256) bf16, rows 19..31 zero
    u16* __restrict__ WoVB)                                // (B,512,32) bf16, cols 19..31 zero
{
    int b = blockIdx.x >> 5, p = blockIdx.x & 31;
    int t = threadIdx.x;
    if (p >= 19) {                  // zero padding
        KB[((long)b * 32 + p) * 256 + t] = 0;
        WoVB[((long)b * 512 + t) * 32 + p] = 0;
        WoVB[((long)b * 512 + 256 + t) * 32 + p] = 0;
        return;
    }
    __shared__ float px[512];
    __shared__ float k1s[256];
    __shared__ float vcol[256];
    for (int i = t; i < 512; i += 256) px[i] = proxy[((long)b * 512 + i) * 19 + p];
    __syncthreads();
    float aK = 0.f, aV = 0.f;
    {
        const float4* pxv = (const float4*)px;
        #pragma unroll 4
        for (int c4 = 0; c4 < 128; ++c4) {
            float4 pv = pxv[c4];
            long base = (long)(c4 * 4) * 256 + t;
            aK += wk1T[base] * pv.x;  aV += wvT[base] * pv.x;
            aK += wk1T[base + 256] * pv.y;  aV += wvT[base + 256] * pv.y;
            aK += wk1T[base + 512] * pv.z;  aV += wvT[base + 512] * pv.z;
            aK += wk1T[base + 768] * pv.w;  aV += wvT[base + 768] * pv.w;
        }
    }
    float k1v = fmaxf(aK * (INV_STD * gk1[t]) + bk1[t], 0.f);
    float vv  = fmaxf(aV * (INV_STD * gv[t])  + bv[t],  0.f);
    k1s[t] = k1v;
    vcol[t] = vv;
    __syncthreads();
    // k2 dot -> KB (coalesced wk2T)
    {
        float a2 = 0.f;
        const float4* k1v4 = (const float4*)k1s;
        #pragma unroll 4
        for (int c4 = 0; c4 < 64; ++c4) {
            float4 kk = k1v4[c4];
            long base = (long)(c4 * 4) * 256 + t;
            a2 += wk2T[base] * kk.x;
            a2 += wk2T[base + 256] * kk.y;
            a2 += wk2T[base + 512] * kk.z;
            a2 += wk2T[base + 768] * kk.w;
        }
        KB[((long)b * 32 + p) * 256 + t] = f2bf(fmaxf(a2 * (INV_STD * gk2[t]) + bk2[t], 0.f));
    }
    // WoV fold: thread t -> channels t and t+256, column p (coalesced woT)
    {
        float a0 = 0.f, a1 = 0.f;
        const float4* vc4 = (const float4*)vcol;
        #pragma unroll 4
        for (int c4 = 0; c4 < 64; ++c4) {
            float4 v4 = vc4[c4];
            long base = (long)(c4 * 4) * 512;
            a0 += woT[base + t] * v4.x;        a1 += woT[base + 256 + t] * v4.x;
            a0 += woT[base + 512 + t] * v4.y;  a1 += woT[base + 768 + t] * v4.y;
            a0 += woT[base + 1024 + t] * v4.z; a1 += woT[base + 1280 + t] * v4.z;
            a0 += woT[base + 1536 + t] * v4.w; a1 += woT[base + 1792 + t] * v4.w;
        }
        WoVB[((long)b * 512 + t) * 32 + p] = f2bf(INV_STD * go[t] * a0);
        WoVB[((long)b * 512 + 256 + t) * 32 + p] = f2bf(INV_STD * go[t + 256] * a1);
    }
}

// ---------------- fully fused: gemm1 -> gemm2 -> attention -> (att · WoV^T) ----------------
// Per 64-pixel block, 4 waves, 2 blocks/CU.  (r13-verified schedule, verbatim.)
__global__ __launch_bounds__(256, 2) void fused_all(
    const float* __restrict__ X,     // (B,512,16384) f32
    const u16* __restrict__ W1,      // (256,512) bf16, K-permuted
    const float* __restrict__ b1,
    const u16* __restrict__ W2,      // (256,256) bf16
    const float* __restrict__ b2,
    const u16* __restrict__ KB,      // (B,32,256) bf16
    const u16* __restrict__ WoVB,    // (B,512,32) bf16
    const float* __restrict__ obias,
    float* __restrict__ out)         // (B,512,16384) f32
{
    __shared__ __align__(16) u16 xs[64 * 64];      //  8 KB, tr-subtiled x tile
    __shared__ __align__(16) u16 lB[2][256 * 32];  // 32 KB, W2 staging (dbuf)
    __shared__ __align__(16) u16 q12s[64 * 264];   // 33 KB: q1 -> q2
    __shared__ __align__(16) u16 atts[64 * 40];    //  5 KB
    int t = threadIdx.x, lane = t & 63, w = t >> 6;
    int l16 = lane & 15, hi = lane >> 4;
    long m0 = (long)blockIdx.x * 64;
    int b = (int)(m0 >> 14);
    int pixg = (int)(m0 & 16383);
    const float* xb = X + (long)b * 512 * 16384 + pixg;
    int ca = t >> 4;       // channel within 16-group
    int aa = t & 15;       // pixel quad
    int rW = lane >> 2;            // staging row within 16-row group
    int cW = (lane & 3) << 3;      // staging col (u16)
    unsigned trb = lds_off(&xs[hi * 64 + l16]);

    // ================= phase A: gemm1, q1 = relu(x^T · W1^T + b1) =================
    {
        f32x4 acc[4][4] = {};
        float4 xr0, xr1, xr2, xr3;
        {
            const float* p0 = xb + (long)ca * 16384 + aa * 4;
            xr0 = *(const float4*)(p0);
            xr1 = *(const float4*)(p0 + 16L * 16384);
            xr2 = *(const float4*)(p0 + 32L * 16384);
            xr3 = *(const float4*)(p0 + 48L * 16384);
        }
        #define STW(XR, P) { \
            int c = (P) * 16 + ca; \
            ushort4 u; u.x = f2bf(XR.x); u.y = f2bf(XR.y); u.z = f2bf(XR.z); u.w = f2bf(XR.w); \
            *(ushort4*)&xs[((aa >> 2) * 16 + (c >> 2)) * 64 + (c & 3) * 16 + (aa & 3) * 4] = u; }
        for (int kt = 0; kt < 8; ++kt) {
            int k0 = kt << 6;
            if (kt > 0) __syncthreads();         // xs free (prev kt's tr_reads done)
            STW(xr0, 0) STW(xr1, 1) STW(xr2, 2) STW(xr3, 3)
            __syncthreads();                     // xs ready
            // W frags first (L2) so their vmcnt wait doesn't chain on the HBM x-prefetch
            bf16x8 bb0[4], bb1[4];
            #pragma unroll
            for (int j = 0; j < 4; ++j) {
                const u16* wr = W1 + (long)(w * 64 + j * 16 + l16) * 512 + k0 + hi * 8;
                bb0[j] = ldg8(wr);
                bb1[j] = ldg8(wr + 32);
            }
            if (kt < 7) {                        // HBM prefetch for next tile
                const float* p0 = xb + (long)(k0 + 64 + ca) * 16384 + aa * 4;
                xr0 = *(const float4*)(p0);
                xr1 = *(const float4*)(p0 + 16L * 16384);
                xr2 = *(const float4*)(p0 + 32L * 16384);
                xr3 = *(const float4*)(p0 + 48L * 16384);
            }
            bf16x4 lo0[4], hh0[4], lo1[4], hh1[4];
            #pragma unroll
            for (int i = 0; i < 4; ++i) {
                unsigned a0 = trb + i * 2048;
                lo0[i] = tr_read(a0);
                hh0[i] = tr_read(a0 + 512);
            }
            #pragma unroll
            for (int i = 0; i < 4; ++i) {
                unsigned a0 = trb + i * 2048 + 1024;
                lo1[i] = tr_read(a0);
                hh1[i] = tr_read(a0 + 512);
            }
            asm volatile("s_waitcnt lgkmcnt(8)" ::: "memory");
            __builtin_amdgcn_sched_barrier(0);
            #pragma unroll
            for (int i = 0; i < 4; ++i) {
                bf16x8 a = __builtin_shufflevector(lo0[i], hh0[i], 0, 1, 2, 3, 4, 5, 6, 7);
                #pragma unroll
                for (int j = 0; j < 4; ++j)
                    acc[i][j] = mfma16(a, bb0[j], acc[i][j]);
            }
            asm volatile("s_waitcnt lgkmcnt(0)" ::: "memory");
            __builtin_amdgcn_sched_barrier(0);
            #pragma unroll
            for (int i = 0; i < 4; ++i) {
                bf16x8 a = __builtin_shufflevector(lo1[i], hh1[i], 0, 1, 2, 3, 4, 5, 6, 7);
                #pragma unroll
                for (int j = 0; j < 4; ++j)
                    acc[i][j] = mfma16(a, bb1[j], acc[i][j]);
            }
        }
        #undef STW
        // epilogue: q1 -> q12s (bf16), and prefetch W2 chunk 0 into lB[0]
        #pragma unroll
        for (int j = 0; j < 4; ++j) {
            int q = w * 4 + j;
            gl_lds16(W2 + (long)(q * 16 + rW) * 256 + cW, &lB[0][q * 512]);
        }
        float bj[4];
        #pragma unroll
        for (int j = 0; j < 4; ++j) bj[j] = b1[w * 64 + j * 16 + l16];
        #pragma unroll
        for (int i = 0; i < 4; ++i)
            #pragma unroll
            for (int r = 0; r < 4; ++r) {
                int pix = i * 16 + hi * 4 + r;
                #pragma unroll
                for (int j = 0; j < 4; ++j) {
                    float v = acc[i][j][r] + bj[j];
                    q12s[pix * 264 + w * 64 + j * 16 + l16] = f2bf(fmaxf(v, 0.f));
                }
            }
    }
    __syncthreads();       // q1 visible + W2 chunk0 staged (full drain required for DMA)
    // ================= phase B: gemm2, q2 = relu(q1 · W2^T + b2) =================
    {
        f32x4 acc[4][4] = {};
        #pragma unroll
        for (int c = 0; c < 8; ++c) {
            int cur = c & 1;
            if (c < 7) {                         // stage next W2 chunk (issue-early)
                int k1 = (c + 1) << 5;
                #pragma unroll
                for (int j = 0; j < 4; ++j) {
                    int q = w * 4 + j;
                    gl_lds16(W2 + (long)(q * 16 + rW) * 256 + k1 + cW, &lB[cur ^ 1][q * 512]);
                }
            }
            bf16x8 a[4], bb[4];
            #pragma unroll
            for (int i = 0; i < 4; ++i)
                a[i] = *(const bf16x8*)&q12s[(i * 16 + l16) * 264 + (c << 5) + hi * 8];
            #pragma unroll
            for (int j = 0; j < 4; ++j)
                bb[j] = *(const bf16x8*)&lB[cur][(w * 64 + j * 16 + l16) * 32 + hi * 8];
            #pragma unroll
            for (int i = 0; i < 4; ++i)
                #pragma unroll
                for (int j = 0; j < 4; ++j)
                    acc[i][j] = mfma16(a[i], bb[j], acc[i][j]);
            __syncthreads();                     // drains next-chunk DMA (overlapped)
        }
        // epilogue: q2 -> q12s (all q1 reads complete after last sync)
        float bj[4];
        #pragma unroll
        for (int j = 0; j < 4; ++j) bj[j] = b2[w * 64 + j * 16 + l16];
        #pragma unroll
        for (int i = 0; i < 4; ++i)
            #pragma unroll
            for (int r = 0; r < 4; ++r) {
                int pix = i * 16 + hi * 4 + r;
                #pragma unroll
                for (int j = 0; j < 4; ++j) {
                    float v = acc[i][j][r] + bj[j];
                    q12s[pix * 264 + w * 64 + j * 16 + l16] = f2bf(fmaxf(v, 0.f));
                }
            }
    }
    __syncthreads();
    // ================= phase C: sim = q2 · KB^T, softmax -> atts =================
    {
        f32x4 s0 = {}, s1 = {};
        #pragma unroll
        for (int ks = 0; ks < 8; ++ks) {
            bf16x8 a = *(const bf16x8*)&q12s[(w * 16 + l16) * 264 + ks * 32 + hi * 8];
            bf16x8 b0 = ldg8(KB + ((long)b * 32 + l16) * 256 + ks * 32 + hi * 8);
            bf16x8 b1v = ldg8(KB + ((long)b * 32 + 16 + l16) * 256 + ks * 32 + hi * 8);
            s0 = mfma16(a, b0, s0);
            s1 = mfma16(a, b1v, s1);
        }
        const float scale = 0.0625f;
        #pragma unroll
        for (int r = 0; r < 4; ++r) {
            float v0 = s0[r] * scale;
            float v1 = s1[r] * scale;
            float mx = fmaxf(v0, v1);
            mx = fmaxf(mx, __shfl_xor(mx, 1));
            mx = fmaxf(mx, __shfl_xor(mx, 2));
            mx = fmaxf(mx, __shfl_xor(mx, 4));
            mx = fmaxf(mx, __shfl_xor(mx, 8));
            float e0 = __expf(v0 - mx);
            float e1 = (l16 < 3) ? __expf(v1 - mx) : 0.f;
            float s = e0 + e1;
            s += __shfl_xor(s, 1);
            s += __shfl_xor(s, 2);
            s += __shfl_xor(s, 4);
            s += __shfl_xor(s, 8);
            float inv = 1.f / s;
            int pix = w * 16 + hi * 4 + r;
            atts[pix * 40 + l16] = f2bf(e0 * inv);
            atts[pix * 40 + 16 + l16] = (l16 < 3) ? f2bf(e1 * inv) : (u16)0;
        }
    }
    __syncthreads();       // atts visible to all waves
    // ================= phase D': out = relu(att · WoV^T + bo); K=32, 0 barriers =================
    {
        bf16x8 av[4], bv[8];
        #pragma unroll
        for (int mf = 0; mf < 4; ++mf)
            av[mf] = *(const bf16x8*)&atts[(mf * 16 + l16) * 40 + hi * 8];
        #pragma unroll
        for (int nf = 0; nf < 8; ++nf)
            bv[nf] = ldg8(WoVB + ((long)b * 512 + w * 128 + nf * 16 + l16) * 32 + hi * 8);
        #pragma unroll
        for (int nf = 0; nf < 8; ++nf) {
            int ch = w * 128 + nf * 16 + l16;
            float bc = obias[ch];
            float* orow = out + ((long)b * 512 + ch) * 16384 + pixg;
            #pragma unroll
            for (int mf = 0; mf < 4; ++mf) {
                f32x4 acc = mfma16(av[mf], bv[nf], (f32x4){0.f, 0.f, 0.f, 0.f});
                float4 v;
                v.x = fmaxf(acc[0] + bc, 0.f);
                v.y = fmaxf(acc[1] + bc, 0.f);
                v.z = fmaxf(acc[2] + bc, 0.f);
                v.w = fmaxf(acc[3] + bc, 0.f);
                *(float4*)&orow[mf * 16 + hi * 4] = v;
            }
        }
    }
}

extern "C" void kernel_launch(void* const* d_in, const int* in_sizes, int n_in,
                              void* d_out, int out_size, void* d_ws, size_t ws_size,
                              hipStream_t stream) {
    const float* x    = (const float*)d_in[0];
    const float* prox = (const float*)d_in[1];
    const float* wq1  = (const float*)d_in[2];
    const float* gq1  = (const float*)d_in[3];
    const float* bq1  = (const float*)d_in[4];
    const float* wq2  = (const float*)d_in[5];
    const float* gq2  = (const float*)d_in[6];
    const float* bq2  = (const float*)d_in[7];
    const float* wk1  = (const float*)d_in[8];
    const float* gk1  = (const float*)d_in[9];
    const float* bk1  = (const float*)d_in[10];
    const float* wk2  = (const float*)d_in[11];
    const float* gk2  = (const float*)d_in[12];
    const float* bk2  = (const float*)d_in[13];
    const float* wv   = (const float*)d_in[14];
    const float* gv   = (const float*)d_in[15];
    const float* bv   = (const float*)d_in[16];
    const float* wo   = (const float*)d_in[17];
    const float* go   = (const float*)d_in[18];
    const float* bo   = (const float*)d_in[19];
    float* out = (float*)d_out;

    char* ws = (char*)d_ws;
    u16*   KB   = (u16*)(ws);                    // 128 KB
    u16*   WoVB = (u16*)(ws + 131072);           // 256 KB
    u16*   WQ1B = (u16*)(ws + 393216);           // 256 KB
    u16*   WQ2B = (u16*)(ws + 655360);           // 128 KB
    float* wk1T = (float*)(ws + 786432);         // 512 KB
    float* wvT  = (float*)(ws + 1310720);        // 512 KB
    float* woT  = (float*)(ws + 1835008);        // 512 KB
    float* wk2T = (float*)(ws + 2359296);        // 256 KB

    prep0<<<880, 256, 0, stream>>>(wq1, gq1, wq2, gq2, wk1, wv, wo, wk2,
                                   WQ1B, WQ2B, wk1T, wvT, woT, wk2T);
    prep1<<<256, 256, 0, stream>>>(prox, wk1T, gk1, bk1, wk2T, gk2, bk2,
                                   wvT, gv, bv, woT, go, KB, WoVB);
    fused_all<<<2048, 256, 0, stream>>>(x, WQ1B, bq1, WQ2B, bq2, KB, WoVB, bo, out);
}